// Round 11
// baseline (27.058 us; speedup 1.0000x reference)
//
#include <hip/hip_runtime.h>
#include <math.h>

// ---------------------------------------------------------------------------
// N-pair Gaussian mixture log-likelihood, factorized form:
//   arg_ij(x) = g_i(x) + g_j(x) + c_ij,  g_i(x) = -0.5 x'prec_i x + x'rhs_i
//   pdf(x)    = u' E u,  u_i = exp(g_i(x)),  E_ij = exp(c_ij + 64 ln2)  [scaled]
//   out       = mean_n( log pdf_n ) + log z_last   (scale folded into Kconst)
// Three kernels (R9 structure). Main: 2 pts/thread (f2 pack, v_pk_fma_f32),
// P[44] precomputed, per-component dot = 4 independent 11-deep chains (ILP),
// __launch_bounds__(256,3) so the compiler has ~170 VGPRs to pipeline with.
// ---------------------------------------------------------------------------

#define LOG2E_F 1.4426950408889634f
#define LN2_F   0.6931471805599453f
#define LN2PI_F 1.8378770664093453f   // ln(2*pi)

// ws layout (float offsets). Staged region = [0,1024) = 256 float4.
#define WS_COEF 0      // 16 rows * 48: per d {lin_d, Q_dd..Q_d7} *log2e; 44 used
#define WS_ES   768    // 160: packed lower-tri E rows, each padded to 16B
#define WS_K    1024   // Kconst = log z_last - 64 ln2  (outside staged region)
#define WS_PART 1088   // per-block partial sums

typedef float f2 __attribute__((ext_vector_type(2)));

// Padded-packed E row offsets (floats)
__device__ const int EOFF_D[16] = {0,4,8,12,16,24,32,40,48,60,72,84,96,112,128,144};

__device__ __forceinline__ float fexp2(float x) {
#if __has_builtin(__builtin_amdgcn_exp2f)
  return __builtin_amdgcn_exp2f(x);
#else
  return exp2f(x);
#endif
}
__device__ __forceinline__ float flog2(float x) {
#if __has_builtin(__builtin_amdgcn_logf)
  return __builtin_amdgcn_logf(x);
#else
  return log2f(x);
#endif
}
__device__ __forceinline__ f2 vfma(float c, f2 x, f2 a) {   // v_pk_fma_f32
  return __builtin_elementwise_fma((f2){c, c}, x, a);
}

// Cholesky: A = C C^T (lower). Only lower triangle of A read. Fully unrolled.
__device__ __forceinline__ void chol8(const float (*A)[8], float (*C)[8]) {
  #pragma unroll
  for (int d = 0; d < 8; ++d) {
    float s = A[d][d];
    #pragma unroll
    for (int m = 0; m < 8; ++m) if (m < d) s -= C[d][m] * C[d][m];
    float cd = sqrtf(s);
    C[d][d] = cd;
    float inv = 1.f / cd;
    #pragma unroll
    for (int e = 0; e < 8; ++e) if (e > d) {
      float t = A[e][d];
      #pragma unroll
      for (int m = 0; m < 8; ++m) if (m < d) t -= C[e][m] * C[d][m];
      C[e][d] = t * inv;
    }
  }
}

// ---------------------------------------------------------------------------
// Kernel A: all setup in one block (unchanged; correctness-proven).
// ---------------------------------------------------------------------------
__global__ __launch_bounds__(256) void gm_setup(const float* __restrict__ mu,
                                                const float* __restrict__ L,
                                                const float* __restrict__ wts,
                                                float* __restrict__ ws) {
  __shared__ float sp[16][72];   // prec[64] + rhs[8] per component
  int tid = threadIdx.x;
  ws[768 + tid] = 0.f;           // zero [768,1024): E pads + tail
  if (tid < 16) {
    int k = tid;
    float Lt[8][8];
    #pragma unroll
    for (int d = 0; d < 8; ++d)
      #pragma unroll
      for (int e = 0; e < 8; ++e)
        Lt[d][e] = (e <= d) ? L[k * 64 + d * 8 + e] : 0.f;
    float A[8][8];
    #pragma unroll
    for (int d = 0; d < 8; ++d)
      #pragma unroll
      for (int e = 0; e <= d; ++e) {
        float s = (d == e) ? 1.f : 0.f;
        #pragma unroll
        for (int m = 0; m < 8; ++m) s += Lt[d][m] * Lt[e][m];
        A[d][e] = s;
        A[e][d] = s;
      }
    float C[8][8];
    chol8(A, C);
    float Ci[8][8];
    #pragma unroll
    for (int d = 0; d < 8; ++d) Ci[d][d] = 1.f / C[d][d];
    #pragma unroll
    for (int e = 0; e < 8; ++e)
      #pragma unroll
      for (int d = 0; d < 8; ++d) if (d > e) {
        float s = 0.f;
        #pragma unroll
        for (int m = 0; m < 8; ++m) if (m >= e && m < d) s += C[d][m] * Ci[m][e];
        Ci[d][e] = -s * Ci[d][d];
      }
    #pragma unroll
    for (int a = 0; a < 8; ++a)
      #pragma unroll
      for (int b = 0; b < 8; ++b) {
        float s = 0.f;
        #pragma unroll
        for (int m = 0; m < 8; ++m) if (m >= a && m >= b) s += Ci[m][a] * Ci[m][b];
        sp[k][a * 8 + b] = s;
      }
    #pragma unroll
    for (int d = 0; d < 8; ++d) {
      float s = 0.f;
      #pragma unroll
      for (int e = 0; e < 8; ++e) s += sp[k][d * 8 + e] * mu[k * 8 + e];
      sp[k][64 + d] = s;
    }
  }
  __syncthreads();

  int p = tid;
  int i = p >> 4, j = p & 15;
  const float* pi = sp[i];
  const float* pj = sp[j];
  float P[8][8], rp[8];
  #pragma unroll
  for (int d = 0; d < 8; ++d) {
    #pragma unroll
    for (int e = 0; e < 8; ++e) P[d][e] = pi[d * 8 + e] + pj[d * 8 + e];
    rp[d] = pi[64 + d] + pj[64 + d];
  }
  float U[8][8];
  chol8(P, U);
  float logdet = 0.f;
  #pragma unroll
  for (int d = 0; d < 8; ++d) logdet += logf(U[d][d]);
  logdet *= 2.f;
  float zf[8];
  #pragma unroll
  for (int d = 0; d < 8; ++d) {
    float s = rp[d];
    #pragma unroll
    for (int m = 0; m < 8; ++m) if (m < d) s -= U[d][m] * zf[m];
    zf[d] = s / U[d][d];
  }
  float y[8];
  #pragma unroll
  for (int dd = 7; dd >= 0; --dd) {
    float s = zf[dd];
    #pragma unroll
    for (int m = 0; m < 8; ++m) if (m > dd) s -= U[m][dd] * y[m];
    y[dd] = s / U[dd][dd];
  }
  float muPmu = 0.f;
  #pragma unroll
  for (int d = 0; d < 8; ++d) muPmu += rp[d] * y[d];
  float c = -0.5f * muPmu + 0.5f * logdet - 32.f * LN2PI_F
          + logf(wts[i]) + logf(wts[j]) + 64.f * LN2_F;
  float Ev = expf(c);
  if (j <= i)   // padded-packed lower triangle; factor 2 folded off-diagonal
    ws[WS_ES + EOFF_D[i] + j] = (i == j) ? Ev : 2.f * Ev;
  if (i == j) { // main-loop coefficient row, interleaved {lin_d, Q_dd..Q_d7}
    float* c0 = ws + WS_COEF + i * 48;
    int q = 0;
    #pragma unroll
    for (int d = 0; d < 8; ++d) {
      c0[q++] = pi[64 + d] * LOG2E_F;                 // lin_d
      #pragma unroll
      for (int e = d; e < 8; ++e) {
        float v = (d == e) ? -0.5f * pi[d * 8 + e] : -pi[d * 8 + e];
        c0[q++] = v * LOG2E_F;                        // Q_de
      }
    }
    c0[44] = 0.f; c0[45] = 0.f; c0[46] = 0.f; c0[47] = 0.f;
  }
  if (p == 255) ws[WS_K] = 0.5f * logdet - 32.f * LN2PI_F - 64.f * LN2_F;
}

// ---------------------------------------------------------------------------
// Kernel B: main N-loop. 2 pts/thread (one f2 pack), 977 blocks (3.8/CU).
// P[44] precomputed once; per component: 11 ds_read_b128 + 4 independent
// 11-deep pk_fma chains. launch_bounds(256,3) -> ~170 VGPR for pipelining.
// ---------------------------------------------------------------------------
__global__ __launch_bounds__(256, 3) void gm_main(const float* __restrict__ X,
                                                  const float* __restrict__ cf,
                                                  float* __restrict__ partials,
                                                  int N) {
  __shared__ float sc[1024];   // [0,768) coef rows; [768,928) padded E; pad
  {
    const float4* cf4 = reinterpret_cast<const float4*>(cf);
    reinterpret_cast<float4*>(sc)[threadIdx.x] = cf4[threadIdx.x];
  }

  const int t = threadIdx.x;
  const int g0i = blockIdx.x * 512 + t;       // point 0
  const int g1i = g0i + 256;                  // point 1 (coalesced)
  const bool act0 = g0i < N, act1 = g1i < N;
  const float4* Xv0 = reinterpret_cast<const float4*>(X) + (size_t)(act0 ? g0i : 0) * 2;
  const float4* Xv1 = reinterpret_cast<const float4*>(X) + (size_t)(act1 ? g1i : 0) * 2;
  float4 a0 = Xv0[0], b0 = Xv0[1];
  float4 a1 = Xv1[0], b1 = Xv1[1];
  __syncthreads();                            // staging complete

  f2 xs[8];
  xs[0] = (f2){a0.x, a1.x}; xs[1] = (f2){a0.y, a1.y};
  xs[2] = (f2){a0.z, a1.z}; xs[3] = (f2){a0.w, a1.w};
  xs[4] = (f2){b0.x, b1.x}; xs[5] = (f2){b0.y, b1.y};
  xs[6] = (f2){b0.z, b1.z}; xs[7] = (f2){b0.w, b1.w};

  // P[q] matches the coef stream order: per d {lin_d -> xs[d], Q_de -> xs[d]*xs[e]}
  constexpr int D_OF[44] = {0,0,0,0,0,0,0,0,0,
                            1,1,1,1,1,1,1,1,
                            2,2,2,2,2,2,2,
                            3,3,3,3,3,3,
                            4,4,4,4,4,
                            5,5,5,5,
                            6,6,6,
                            7,7};
  constexpr int E_OF[44] = {-1,0,1,2,3,4,5,6,7,
                            -1,1,2,3,4,5,6,7,
                            -1,2,3,4,5,6,7,
                            -1,3,4,5,6,7,
                            -1,4,5,6,7,
                            -1,5,6,7,
                            -1,6,7,
                            -1,7};
  f2 P[44];
  #pragma unroll
  for (int q = 0; q < 44; ++q)
    P[q] = (E_OF[q] < 0) ? xs[D_OF[q]] : xs[D_OF[q]] * xs[E_OF[q]];  // v_pk_mul

  // u[i] = exp2(C_i . P)  (log2e pre-folded into coefficients)
  f2 u[16];
  #pragma unroll
  for (int i = 0; i < 16; ++i) {
    const float4* c4 = reinterpret_cast<const float4*>(sc + i * 48);
    f2 A0 = (f2){0.f, 0.f}, A1 = (f2){0.f, 0.f};
    f2 A2 = (f2){0.f, 0.f}, A3 = (f2){0.f, 0.f};
    #pragma unroll
    for (int v = 0; v < 11; ++v) {            // 11x ds_read_b128 broadcast
      float4 w = c4[v];
      A0 = vfma(w.x, P[4 * v + 0], A0);       // 4 independent 11-deep chains
      A1 = vfma(w.y, P[4 * v + 1], A1);
      A2 = vfma(w.z, P[4 * v + 2], A2);
      A3 = vfma(w.w, P[4 * v + 3], A3);
    }
    f2 g = (A0 + A1) + (A2 + A3);
    u[i] = (f2){fexp2(g.x), fexp2(g.y)};
  }

  // pdf = sum_i u_i * (padded row_i . u)   [diag=E'_ii, off=2E'_ij, pads=0]
  constexpr int EOFF[16]  = {0,4,8,12,16,24,32,40,48,60,72,84,96,112,128,144};
  constexpr int ELEN4[16] = {1,1,1,1,2,2,2,2,3,3,3,3,4,4,4,4};
  const float4* es4 = reinterpret_cast<const float4*>(sc + 768);
  f2 pdf = (f2){0.f, 0.f};
  #pragma unroll
  for (int i = 0; i < 16; ++i) {
    f2 s0 = (f2){0.f, 0.f}, s1 = (f2){0.f, 0.f};
    #pragma unroll
    for (int q4 = 0; q4 < ELEN4[i]; ++q4) {   // ds_read_b128 per 4 E entries
      float4 ev = es4[EOFF[i] / 4 + q4];
      const int j = q4 * 4;
      s0 = vfma(ev.x, u[j + 0], s0);
      s1 = vfma(ev.y, u[j + 1], s1);
      s0 = vfma(ev.z, u[j + 2], s0);
      s1 = vfma(ev.w, u[j + 3], s1);
    }
    pdf = __builtin_elementwise_fma(u[i], s0 + s1, pdf);
  }
  float lsum = 0.f;
  if (act0) lsum += flog2(pdf.x);
  if (act1) lsum += flog2(pdf.y);

  // deterministic block reduction of sum(log2 pdf)
  #pragma unroll
  for (int off = 32; off > 0; off >>= 1) lsum += __shfl_down(lsum, off, 64);
  __shared__ float wsum[4];
  int lane = threadIdx.x & 63, wid = threadIdx.x >> 6;
  if (lane == 0) wsum[wid] = lsum;
  __syncthreads();
  if (threadIdx.x == 0)
    partials[blockIdx.x] = (wsum[0] + wsum[1]) + (wsum[2] + wsum[3]);
}

// ---------------------------------------------------------------------------
// Kernel C: deterministic final reduction (fixed-order strided + tree)
// ---------------------------------------------------------------------------
__global__ __launch_bounds__(256) void gm_final(const float* __restrict__ ws,
                                                float* __restrict__ out,
                                                int nb, float invN) {
  const float* partials = ws + WS_PART;
  float s = 0.f;
  for (int t = threadIdx.x; t < nb; t += 256) s += partials[t];
  #pragma unroll
  for (int off = 32; off > 0; off >>= 1) s += __shfl_down(s, off, 64);
  __shared__ float wsum[4];
  int lane = threadIdx.x & 63, wid = threadIdx.x >> 6;
  if (lane == 0) wsum[wid] = s;
  __syncthreads();
  if (threadIdx.x == 0) {
    float tot = (wsum[0] + wsum[1]) + (wsum[2] + wsum[3]);
    // mean(ln pdf_true) + ln z_last = ln2 * mean(log2 pdf_scaled) + Kconst
    out[0] = tot * LN2_F * invN + ws[WS_K];
  }
}

extern "C" void kernel_launch(void* const* d_in, const int* in_sizes, int n_in,
                              void* d_out, int out_size, void* d_ws, size_t ws_size,
                              hipStream_t stream) {
  const float* X = (const float*)d_in[0];
  const float* mu = (const float*)d_in[1];
  const float* L = (const float*)d_in[2];
  const float* wts = (const float*)d_in[3];
  // d_in[4] ("it") is unused by the reference math.
  float* ws = (float*)d_ws;
  float* out = (float*)d_out;
  int N = in_sizes[0] / 8;
  int nb = (N + 511) / 512;              // 2 points per thread, 256 threads
  gm_setup<<<1, 256, 0, stream>>>(mu, L, wts, ws);
  gm_main<<<nb, 256, 0, stream>>>(X, ws, ws + WS_PART, N);
  gm_final<<<1, 256, 0, stream>>>(ws, out, nb, 1.0f / (float)N);
}